// Round 4
// baseline (151.838 us; speedup 1.0000x reference)
//
#include <hip/hip_runtime.h>
#include <math.h>

// Problem constants (fixed by setup_inputs)
constexpr int B = 32;
constexpr int N = 65;    // seq_len + 1
constexpr int D = 512;
constexpr int S = 64;    // N - 1
constexpr int M = B * N; // 2080 rows for the QK projection GEMM

// out0 layout: [B, S, S+1, D] = 68,157,440 floats. The b=31 block
// (last 2,129,920 floats) is EXACTLY q (M*D) + kT (B*D*N) — we stage q/kT
// there; K4's bit-gated dense fill of the b>=30 suffix overwrites it.
constexpr size_t OUT0_ELEMS = (size_t)B * S * (S + 1) * D;       // 68,157,440
constexpr size_t Q_ELEMS    = (size_t)M * D;                      // 1,064,960
constexpr size_t KT_ELEMS   = (size_t)B * D * N;                  // 1,064,960
constexpr size_t STAGE_BASE = OUT0_ELEMS - Q_ELEMS - KT_ELEMS;    // row 1984
constexpr int OUT0_F4 = (int)(OUT0_ELEMS / 4);                    // 17,039,360

constexpr int ROW_F4 = (S + 1) * (D / 4);          // 8320 f4 per (b,i) row
constexpr int ROWS_SCATTER = 1920;                 // b in [0,30): zero+scatter
constexpr int F_C = ROW_F4 * ROWS_SCATTER;         // 15,974,400 (gated suffix after)
constexpr int F_A = 10000000;                      // K1 zero-fills [0, F_A)    ~160 MB
constexpr int F_B = 14400000;                      // K2 zero-fills [F_A, F_B)  ~70 MB
                                                   // K3 zero-fills [F_B, F_C)  ~25 MB

// Grids
constexpr int NG_GEMM = 264;    // 33 m-tiles x 8 n-tiles (q and k fused)
constexpr int NG_FILL = 1536;
constexpr int N2_ATTN = 256;    // 8 rows per block (4 waves x 2 rows)
constexpr int N2_FILL = 768;
constexpr int N3_FILL = 256;
constexpr int N4_DENSE = 1024;  // gated fill of [F_C, OUT0_F4)
constexpr int N4_TAIL  = 130;   // (B*S + B*S*S)/4 = 33,280 f4

// ---------------------------------------------------------------------------
// K1: fused projection GEMM. q = nve@Wq^T+bq (row-major), k likewise but
// stored transposed per batch kT[b][d][n]. One block computes BOTH q and k
// for its 64x64 tile (shared A staging). BK=64, 4x4 microtile, 256 thr.
// Plus zero-fill of out0 [0, F_A).
// ---------------------------------------------------------------------------
__global__ __launch_bounds__(256) void k1_gemm_fill(
    const float* __restrict__ nve, const float* __restrict__ Wq,
    const float* __restrict__ bq, const float* __restrict__ Wk,
    const float* __restrict__ bk, float* __restrict__ out)
{
    __shared__ float As[64][68];
    __shared__ float Qs[64][68];
    __shared__ float Ks[64][68];

    const int gid = blockIdx.x;
    const int tid = threadIdx.x;

    if (gid < NG_GEMM) {
        const int bm = (gid % 33) * 64;
        const int bn = (gid / 33) * 64;

        float* q  = out + STAGE_BASE;            // [M][D]
        float* kT = q + Q_ELEMS;                 // [B][D][N]

        const int tr = tid / 16;
        const int tc = tid % 16;
        float accq[4][4] = {};
        float acck[4][4] = {};

        for (int k0 = 0; k0 < D; k0 += 64) {
            #pragma unroll
            for (int p = 0; p < 4; ++p) {
                const int idx = p * 256 + tid;       // 0..1023
                const int row = idx >> 4;            // 0..63
                const int c4  = (idx & 15) * 4;      // 0..60
                const int gm = bm + row;
                float4 v = make_float4(0.f, 0.f, 0.f, 0.f);
                if (gm < M) v = *(const float4*)&nve[(size_t)gm * D + k0 + c4];
                As[c4 + 0][row] = v.x; As[c4 + 1][row] = v.y;
                As[c4 + 2][row] = v.z; As[c4 + 3][row] = v.w;
                float4 wq = *(const float4*)&Wq[(size_t)(bn + row) * D + k0 + c4];
                Qs[c4 + 0][row] = wq.x; Qs[c4 + 1][row] = wq.y;
                Qs[c4 + 2][row] = wq.z; Qs[c4 + 3][row] = wq.w;
                float4 wk = *(const float4*)&Wk[(size_t)(bn + row) * D + k0 + c4];
                Ks[c4 + 0][row] = wk.x; Ks[c4 + 1][row] = wk.y;
                Ks[c4 + 2][row] = wk.z; Ks[c4 + 3][row] = wk.w;
            }
            __syncthreads();

            #pragma unroll 8
            for (int kk = 0; kk < 64; ++kk) {
                float a[4], wq[4], wk[4];
                #pragma unroll
                for (int u = 0; u < 4; ++u) a[u]  = As[kk][tr * 4 + u];
                #pragma unroll
                for (int u = 0; u < 4; ++u) wq[u] = Qs[kk][tc * 4 + u];
                #pragma unroll
                for (int u = 0; u < 4; ++u) wk[u] = Ks[kk][tc * 4 + u];
                #pragma unroll
                for (int i = 0; i < 4; ++i)
                    #pragma unroll
                    for (int j = 0; j < 4; ++j) {
                        accq[i][j] += a[i] * wq[j];
                        acck[i][j] += a[i] * wk[j];
                    }
            }
            __syncthreads();
        }

        #pragma unroll
        for (int i = 0; i < 4; ++i) {
            const int gm = bm + tr * 4 + i;
            if (gm >= M) continue;
            const int b = gm / N;
            const int n = gm % N;
            float4 v;
            v.x = accq[i][0] + bq[bn + tc * 4 + 0];
            v.y = accq[i][1] + bq[bn + tc * 4 + 1];
            v.z = accq[i][2] + bq[bn + tc * 4 + 2];
            v.w = accq[i][3] + bq[bn + tc * 4 + 3];
            *(float4*)&q[(size_t)gm * D + bn + tc * 4] = v;
            #pragma unroll
            for (int j = 0; j < 4; ++j) {
                const int gd = bn + tc * 4 + j;
                kT[(size_t)b * D * N + (size_t)gd * N + n] = acck[i][j] + bk[gd];
            }
        }
    } else {
        const float4 z = make_float4(0.f, 0.f, 0.f, 0.f);
        float4* o4 = (float4*)out;
        const int nthr = NG_FILL * 256;
        for (int f = (gid - NG_GEMM) * 256 + tid; f < F_A; f += nthr)
            o4[f] = z;
    }
}

// ---------------------------------------------------------------------------
// K2: attention + membership. Block = 4 waves, each wave owns 2 attn rows.
// Lane l <-> column l+1 (coalesced kT[b][d][1..64] reads); col 0 kept as a
// lane-uniform extra accumulator. Softmax over 65 values via shfl butterfly;
// member bits via __ballot. Plus zero-fill of [F_A, F_B).
// ---------------------------------------------------------------------------
__global__ __launch_bounds__(256) void k2_attn(
    const float* __restrict__ out, unsigned long long* __restrict__ mem,
    float* __restrict__ outw)
{
    const int gid = blockIdx.x;
    const int t = threadIdx.x;

    if (gid < N2_ATTN) {
        const float* q  = out + STAGE_BASE;
        const float* kT = q + Q_ELEMS;

        const int b  = gid >> 3;           // 0..31
        const int r0 = (gid & 7) * 8;      // first member-row of this block

        __shared__ float qs[8][D];

        #pragma unroll
        for (int p = 0; p < 4; ++p) {
            const int idx = p * 256 + t;          // 0..1023 f4
            const int rl  = idx >> 7;             // 0..7
            const int d4  = idx & 127;
            const int i   = r0 + rl + 1;          // attn row
            *(float4*)&qs[rl][d4 * 4] =
                *(const float4*)&q[((size_t)b * N + i) * D + d4 * 4];
        }
        __syncthreads();

        const int w = t >> 6;              // wave 0..3
        const int l = t & 63;              // lane = col-1
        const int rA = w * 2, rB = w * 2 + 1;
        const int iA = r0 + rA + 1, iB = r0 + rB + 1;

        const float* kp = &kT[(size_t)b * D * N];
        float aA = 0.f, aB = 0.f, a0A = 0.f, a0B = 0.f;
        #pragma unroll 4
        for (int d = 0; d < D; ++d) {
            const float kv0 = kp[d * N];
            const float kv  = kp[d * N + 1 + l];
            const float qa  = qs[rA][d];
            const float qb  = qs[rB][d];
            aA  += qa * kv;  aB  += qb * kv;
            a0A += qa * kv0; a0B += qb * kv0;
        }

        const float c = 0.044194173824159216f;  // 1/sqrt(512)
        #pragma unroll
        for (int pass = 0; pass < 2; ++pass) {
            const int i = pass ? iB : iA;
            float s  = (pass ? aB : aA) * c;
            const float s0 = (pass ? a0B : a0A) * c;
            if (l == i - 1) s = 0.f;            // diag of [1:,1:] zeroed pre-softmax
            float m = s;
            #pragma unroll
            for (int off = 32; off; off >>= 1) m = fmaxf(m, __shfl_xor(m, off));
            m = fmaxf(m, s0);
            float e = expf(s - m);
            float sum = e;
            #pragma unroll
            for (int off = 32; off; off >>= 1) sum += __shfl_xor(sum, off);
            sum += expf(s0 - m);
            const bool bit = (e / sum > 0.05f) || (l == i - 1);
            unsigned long long mask = __ballot(bit);
            if (l == 0) mem[b * S + i - 1] = mask;
        }
    } else {
        const float4 z = make_float4(0.f, 0.f, 0.f, 0.f);
        float4* o4 = (float4*)outw;
        const int nthr = N2_FILL * 256;
        for (int f = F_A + (gid - N2_ATTN) * 256 + t; f < F_B; f += nthr)
            o4[f] = z;
    }
}

// ---------------------------------------------------------------------------
// K3: greedy sequential clustering (block 0; mem staged through LDS) +
// zero-fill of [F_B, F_C).
// ---------------------------------------------------------------------------
__global__ __launch_bounds__(256) void k3_cluster(
    const unsigned long long* __restrict__ mem,
    unsigned long long* __restrict__ sel,
    unsigned long long* __restrict__ lead,
    float* __restrict__ out)
{
    const int gid = blockIdx.x;
    const int t = threadIdx.x;
    if (gid == 0) {
        __shared__ unsigned long long lmem[B * S];
        #pragma unroll
        for (int p = 0; p < 8; ++p) lmem[p * 256 + t] = mem[p * 256 + t];
        __syncthreads();
        if (t < B) {
            const int b = t;
            unsigned long long used = 0ull, lb = 0ull;
            for (int i = 0; i < S; ++i) {
                const unsigned long long row = lmem[b * S + i];
                const bool active = !((used >> i) & 1ull);
                const unsigned long long sl = active ? row : 0ull;
                used |= sl;
                lb |= (unsigned long long)active << i;
                sel[b * S + i] = sl;
            }
            lead[b] = lb;
        }
    } else {
        const float4 z = make_float4(0.f, 0.f, 0.f, 0.f);
        float4* o4 = (float4*)out;
        const int nthr = N3_FILL * 256;
        for (int f = F_B + (gid - 1) * 256 + t; f < F_C; f += nthr)
            o4[f] = z;
    }
}

// ---------------------------------------------------------------------------
// K4: (C) scatter nonzero rows for b<30 (zeros already written);
// (A) bit-gated dense fill of rows [1920, 2048) — covers the staging region;
// (B) leader/member tail.
// ---------------------------------------------------------------------------
__global__ __launch_bounds__(256) void k4_finish(
    const float* __restrict__ nve, const float* __restrict__ cls,
    const unsigned long long* __restrict__ sel,
    const unsigned long long* __restrict__ lead,
    float* __restrict__ out)
{
    const int gid = blockIdx.x;
    const int t = threadIdx.x;

    if (gid < ROWS_SCATTER) {
        const int b = gid >> 6;
        const int i = gid & 63;
        const unsigned long long lb = lead[b];
        const unsigned long long sb = sel[b * S + i];
        const int h = t >> 7;
        const int tt = t & 127;
        float4* slot0 = (float4*)(out + (((size_t)b * S + i) * (S + 1)) * D);
        for (int s = h; s <= S; s += 2) {
            bool on = (s == 0) ? ((lb >> i) & 1ull) : ((sb >> (s - 1)) & 1ull);
            if (!on) continue;
            const float* src = (s == 0) ? cls : &nve[((size_t)b * N + s) * D];
            slot0[(size_t)s * 128 + tt] = ((const float4*)src)[tt];
        }
    } else if (gid < ROWS_SCATTER + N4_DENSE) {
        float4* o4 = (float4*)out;
        const int nthr = N4_DENSE * 256;
        for (int f = F_C + (gid - ROWS_SCATTER) * 256 + t; f < OUT0_F4; f += nthr) {
            const int d4 = f & 127;
            const int slot = f >> 7;
            const int s = slot % (S + 1);
            const int row = slot / (S + 1);
            const int i = row & 63;
            const int b = row >> 6;
            bool on;
            const float* src;
            if (s == 0) {
                on = (lead[b] >> i) & 1ull;
                src = &cls[d4 * 4];
            } else {
                on = (sel[b * S + i] >> (s - 1)) & 1ull;
                src = &nve[((size_t)b * N + s) * D + d4 * 4];
            }
            float4 v = make_float4(0.f, 0.f, 0.f, 0.f);
            if (on) v = *(const float4*)src;
            o4[f] = v;
        }
    } else {
        const int f = (gid - ROWS_SCATTER - N4_DENSE) * 256 + t;   // f4 index
        float* tail = out + OUT0_ELEMS;
        float4 v;
        #pragma unroll
        for (int c = 0; c < 4; ++c) {
            const int idx = f * 4 + c;
            float x;
            if (idx < B * S) {
                x = (float)((lead[idx / S] >> (idx % S)) & 1ull);
            } else {
                const int m = idx - B * S;
                const int b = m / (S * S);
                const int rem = m % (S * S);
                x = (float)((sel[b * S + rem / S] >> (rem % S)) & 1ull);
            }
            ((float*)&v)[c] = x;
        }
        *(float4*)&tail[(size_t)f * 4] = v;
    }
}

extern "C" void kernel_launch(void* const* d_in, const int* in_sizes, int n_in,
                              void* d_out, int out_size, void* d_ws, size_t ws_size,
                              hipStream_t stream) {
    const float* nve = (const float*)d_in[1];
    const float* Wq  = (const float*)d_in[2];
    const float* bq  = (const float*)d_in[3];
    const float* Wk  = (const float*)d_in[4];
    const float* bk  = (const float*)d_in[5];
    const float* cls = (const float*)d_in[6];

    float* out = (float*)d_out;

    unsigned long long* mem  = (unsigned long long*)d_ws;       // B*S
    unsigned long long* sel  = mem + B * S;                     // B*S
    unsigned long long* lead = sel + B * S;                     // B

    k1_gemm_fill<<<NG_GEMM + NG_FILL, 256, 0, stream>>>(nve, Wq, bq, Wk, bk, out);
    k2_attn<<<N2_ATTN + N2_FILL, 256, 0, stream>>>(out, mem, out);
    k3_cluster<<<1 + N3_FILL, 256, 0, stream>>>(mem, sel, lead, out);
    k4_finish<<<ROWS_SCATTER + N4_DENSE + N4_TAIL, 256, 0, stream>>>(nve, cls, sel, lead, out);
}

// Round 5
// 134.010 us; speedup vs baseline: 1.1330x; 1.1330x over previous
//
#include <hip/hip_runtime.h>
#include <math.h>

// Problem constants (fixed by setup_inputs)
constexpr int B = 32;
constexpr int N = 65;    // seq_len + 1
constexpr int D = 512;
constexpr int S = 64;    // N - 1
constexpr int M = B * N; // 2080 projection rows

// out0 = [B, S, S+1, D] = 68,157,440 floats. The b=31 block (last 2*M*D
// floats) stages q (M*D) + kT (M*D); K3's gated dense fill overwrites it.
constexpr size_t OUT0_ELEMS = (size_t)B * S * (S + 1) * D;   // 68,157,440
constexpr size_t Q_ELEMS    = (size_t)M * D;                  // 1,064,960
constexpr size_t STAGE_BASE = OUT0_ELEMS - 2 * Q_ELEMS;       // row 1984 start
constexpr int ROW_F4 = (S + 1) * (D / 4);                     // 8320 f4 per (b,i) row

// Zero-fill split (row-aligned). K1 fills rows [0,R_K1), K2 [R_K1,R_PRE);
// K3 writes rows [R_PRE,2048) gated-dense (no pre-zero needed there).
constexpr int R_K1  = 1130;
constexpr int R_PRE = 1430;
constexpr int F_A = R_K1 * ROW_F4;    // 9,401,600 f4  (~150 MB)
constexpr int F_B = R_PRE * ROW_F4;   // 11,897,600 f4 (~40 MB more)

// Grids
constexpr int NG_GEMM = 1040;  // 65 m-tiles x 8 n-tiles x 2 matrices
constexpr int NG_FILL = 1024;
constexpr int N2_ATTN = 256;   // 8 attn rows per block
constexpr int N2_FILL = 512;
constexpr int N3_ROWS = 2048;  // one block per (b,i) output row
constexpr int N3_TAIL = 32;    // one block per batch for leader/member

// ---------------------------------------------------------------------------
// K1: projection GEMM (q = nve@Wq^T+bq row-major; kT[b][d][n]) at high
// occupancy: 32x64 tiles, 1040 blocks, 2x4 microtile, BK=64, 25.5 KB LDS.
// Plus zero-fill of out0 rows [0, R_K1).
// ---------------------------------------------------------------------------
__global__ __launch_bounds__(256) void k1_gemm_fill(
    const float* __restrict__ nve, const float* __restrict__ Wq,
    const float* __restrict__ bq, const float* __restrict__ Wk,
    const float* __restrict__ bk, float* __restrict__ out)
{
    __shared__ float As[64][34];   // [K][m-row], b64 reads aligned
    __shared__ float Ws[64][68];   // [K][n-col], XOR-swizzled, b128 reads

    const int gid = blockIdx.x;
    const int tid = threadIdx.x;

    if (gid < NG_GEMM) {
        const int mat = gid >= (NG_GEMM / 2);
        const int t   = mat ? gid - NG_GEMM / 2 : gid;
        const int bm  = (t % 65) * 32;     // 65*32 = 2080 = M exactly
        const int bn  = (t / 65) * 64;
        const float* W    = mat ? Wk : Wq;
        const float* bias = mat ? bk : bq;

        float* q  = out + STAGE_BASE;      // [M][D]
        float* kT = q + Q_ELEMS;           // [B][D][N]

        const int tn4 = (tid & 15) * 4;    // 4 output cols
        const int tm2 = (tid >> 4) * 2;    // 2 output rows

        float4 acc0 = make_float4(0.f, 0.f, 0.f, 0.f);
        float4 acc1 = make_float4(0.f, 0.f, 0.f, 0.f);

        for (int k0 = 0; k0 < D; k0 += 64) {
            #pragma unroll
            for (int p = 0; p < 2; ++p) {          // A tile: 32 rows x 16 f4
                const int idx = p * 256 + tid;
                const int row = idx >> 4;
                const int c4  = (idx & 15) * 4;
                const float4 v = *(const float4*)&nve[(size_t)(bm + row) * D + k0 + c4];
                As[c4 + 0][row] = v.x; As[c4 + 1][row] = v.y;
                As[c4 + 2][row] = v.z; As[c4 + 3][row] = v.w;
            }
            #pragma unroll
            for (int p = 0; p < 4; ++p) {          // W tile: 64 rows x 16 f4
                const int idx = p * 256 + tid;
                const int row = idx >> 4;
                const int c4  = (idx & 15) * 4;
                const float4 v = *(const float4*)&W[(size_t)(bn + row) * D + k0 + c4];
                const int pc = row ^ (((c4 >> 2) & 7) << 2);   // swizzled n-col
                Ws[c4 + 0][pc] = v.x; Ws[c4 + 1][pc] = v.y;
                Ws[c4 + 2][pc] = v.z; Ws[c4 + 3][pc] = v.w;
            }
            __syncthreads();

            #pragma unroll
            for (int kk = 0; kk < 64; ++kk) {
                const float a0 = As[kk][tm2];
                const float a1 = As[kk][tm2 + 1];
                const float4 w =
                    *(const float4*)&Ws[kk][tn4 ^ (((kk >> 2) & 7) << 2)];
                acc0.x += a0 * w.x; acc0.y += a0 * w.y;
                acc0.z += a0 * w.z; acc0.w += a0 * w.w;
                acc1.x += a1 * w.x; acc1.y += a1 * w.y;
                acc1.z += a1 * w.z; acc1.w += a1 * w.w;
            }
            __syncthreads();
        }

        const int gm0 = bm + tm2;
        const float4 b4 = *(const float4*)&bias[bn + tn4];
        if (mat == 0) {
            float4 r;
            r.x = acc0.x + b4.x; r.y = acc0.y + b4.y;
            r.z = acc0.z + b4.z; r.w = acc0.w + b4.w;
            *(float4*)&q[(size_t)gm0 * D + bn + tn4] = r;
            r.x = acc1.x + b4.x; r.y = acc1.y + b4.y;
            r.z = acc1.z + b4.z; r.w = acc1.w + b4.w;
            *(float4*)&q[(size_t)(gm0 + 1) * D + bn + tn4] = r;
        } else {
            #pragma unroll
            for (int rr = 0; rr < 2; ++rr) {
                const int gm = gm0 + rr;
                const int b = gm / N;
                const int n = gm % N;
                const float* ac = rr ? (const float*)&acc1 : (const float*)&acc0;
                const float* bi = (const float*)&b4;
                #pragma unroll
                for (int j = 0; j < 4; ++j) {
                    const int gd = bn + tn4 + j;
                    kT[(size_t)b * D * N + (size_t)gd * N + n] = ac[j] + bi[j];
                }
            }
        }
    } else {
        const float4 z = make_float4(0.f, 0.f, 0.f, 0.f);
        float4* o4 = (float4*)out;
        const int nthr = NG_FILL * 256;
        for (int f = (gid - NG_GEMM) * 256 + tid; f < F_A; f += nthr)
            o4[f] = z;
    }
}

// ---------------------------------------------------------------------------
// K2: attention + membership. Block = 4 waves x 2 attn rows. Lane l <-> col
// l+1 (coalesced kT reads); col 0 as lane-uniform extra accumulator.
// Softmax via shfl butterfly; member bits via __ballot.
// Plus zero-fill of rows [R_K1, R_PRE).
// ---------------------------------------------------------------------------
__global__ __launch_bounds__(256) void k2_attn(
    const float* __restrict__ out, unsigned long long* __restrict__ mem,
    float* __restrict__ outw)
{
    const int gid = blockIdx.x;
    const int t = threadIdx.x;

    if (gid < N2_ATTN) {
        const float* q  = out + STAGE_BASE;
        const float* kT = q + Q_ELEMS;

        const int b  = gid >> 3;
        const int r0 = (gid & 7) * 8;

        __shared__ float qs[8][D];

        #pragma unroll
        for (int p = 0; p < 4; ++p) {
            const int idx = p * 256 + t;
            const int rl  = idx >> 7;
            const int d4  = idx & 127;
            const int i   = r0 + rl + 1;
            *(float4*)&qs[rl][d4 * 4] =
                *(const float4*)&q[((size_t)b * N + i) * D + d4 * 4];
        }
        __syncthreads();

        const int w = t >> 6;
        const int l = t & 63;
        const int rA = w * 2, rB = w * 2 + 1;
        const int iA = r0 + rA + 1, iB = r0 + rB + 1;

        const float* kp = &kT[(size_t)b * D * N];
        float aA = 0.f, aB = 0.f, a0A = 0.f, a0B = 0.f;
        #pragma unroll 4
        for (int d = 0; d < D; ++d) {
            const float kv0 = kp[d * N];
            const float kv  = kp[d * N + 1 + l];
            const float qa  = qs[rA][d];
            const float qb  = qs[rB][d];
            aA  += qa * kv;  aB  += qb * kv;
            a0A += qa * kv0; a0B += qb * kv0;
        }

        const float c = 0.044194173824159216f;  // 1/sqrt(512)
        #pragma unroll
        for (int pass = 0; pass < 2; ++pass) {
            const int i = pass ? iB : iA;
            float s  = (pass ? aB : aA) * c;
            const float s0 = (pass ? a0B : a0A) * c;
            if (l == i - 1) s = 0.f;            // diag of [1:,1:] zeroed pre-softmax
            float m = s;
            #pragma unroll
            for (int off = 32; off; off >>= 1) m = fmaxf(m, __shfl_xor(m, off));
            m = fmaxf(m, s0);
            float e = expf(s - m);
            float sum = e;
            #pragma unroll
            for (int off = 32; off; off >>= 1) sum += __shfl_xor(sum, off);
            sum += expf(s0 - m);
            const bool bit = (e / sum > 0.05f) || (l == i - 1);
            unsigned long long mask = __ballot(bit);
            if (l == 0) mem[b * S + i - 1] = mask;
        }
    } else {
        const float4 z = make_float4(0.f, 0.f, 0.f, 0.f);
        float4* o4 = (float4*)outw;
        const int nthr = N2_FILL * 256;
        for (int f = F_A + (gid - N2_ATTN) * 256 + t; f < F_B; f += nthr)
            o4[f] = z;
    }
}

// ---------------------------------------------------------------------------
// K3: finish. Every block recomputes its batch's greedy clustering from mem
// (wave-0 shfl loop, ~64 iters) -> no separate cluster kernel.
//   gid < N3_ROWS: output row gid. Rows < R_PRE: scatter "on" slots only
//   (zeros pre-written). Rows >= R_PRE: gated dense (writes zeros too; covers
//   the q/kT staging region). gid >= N3_ROWS: leader/member tail per batch.
// ---------------------------------------------------------------------------
__global__ __launch_bounds__(256) void k3_finish(
    const float* __restrict__ nve, const float* __restrict__ cls,
    const unsigned long long* __restrict__ mem, float* __restrict__ out)
{
    const int gid = blockIdx.x;
    const int t = threadIdx.x;
    const int b = (gid < N3_ROWS) ? (gid >> 6) : (gid - N3_ROWS);

    __shared__ unsigned long long s_sel[S];
    __shared__ unsigned long long s_lead;

    if (t < 64) {
        const unsigned long long myrow = mem[b * S + t];
        unsigned long long used = 0ull, lb = 0ull, mysel = 0ull;
        for (int i = 0; i < S; ++i) {
            const unsigned long long row = __shfl(myrow, i, 64);
            const bool active = !((used >> i) & 1ull);
            const unsigned long long sl = active ? row : 0ull;
            used |= sl;
            lb |= (unsigned long long)active << i;
            if (t == i) mysel = sl;
        }
        s_sel[t] = mysel;
        if (t == 0) s_lead = lb;
    }
    __syncthreads();

    if (gid < N3_ROWS) {
        const int i = gid & 63;
        const bool dense = gid >= R_PRE;
        const unsigned long long sb = s_sel[i];
        const bool lbit = (s_lead >> i) & 1ull;
        float4* slot0 = (float4*)(out + (size_t)gid * (S + 1) * D);
        const int h = t >> 7;
        const int tt = t & 127;
        const float4 z = make_float4(0.f, 0.f, 0.f, 0.f);
        for (int s = h; s <= S; s += 2) {
            const bool on = (s == 0) ? lbit : ((sb >> (s - 1)) & 1ull);
            if (on) {
                const float* src = (s == 0) ? cls : &nve[((size_t)b * N + s) * D];
                slot0[(size_t)s * 128 + tt] = ((const float4*)src)[tt];
            } else if (dense) {
                slot0[(size_t)s * 128 + tt] = z;
            }
        }
    } else {
        float* tail = out + OUT0_ELEMS;
        if (t < 16) {   // leader [B,S]: 16 f4 per batch
            float4 v;
            v.x = (float)((s_lead >> (t * 4 + 0)) & 1ull);
            v.y = (float)((s_lead >> (t * 4 + 1)) & 1ull);
            v.z = (float)((s_lead >> (t * 4 + 2)) & 1ull);
            v.w = (float)((s_lead >> (t * 4 + 3)) & 1ull);
            ((float4*)tail)[b * 16 + t] = v;
        }
        // member [B,S,S]: 1024 f4 per batch
        float4* m4 = (float4*)tail + (B * S / 4) + b * (S * S / 4);
        #pragma unroll
        for (int p = 0; p < 4; ++p) {
            const int f  = p * 256 + t;
            const int i  = f >> 4;
            const int j4 = (f & 15) * 4;
            const unsigned long long sr = s_sel[i];
            float4 v;
            v.x = (float)((sr >> (j4 + 0)) & 1ull);
            v.y = (float)((sr >> (j4 + 1)) & 1ull);
            v.z = (float)((sr >> (j4 + 2)) & 1ull);
            v.w = (float)((sr >> (j4 + 3)) & 1ull);
            m4[f] = v;
        }
    }
}

extern "C" void kernel_launch(void* const* d_in, const int* in_sizes, int n_in,
                              void* d_out, int out_size, void* d_ws, size_t ws_size,
                              hipStream_t stream) {
    const float* nve = (const float*)d_in[1];
    const float* Wq  = (const float*)d_in[2];
    const float* bq  = (const float*)d_in[3];
    const float* Wk  = (const float*)d_in[4];
    const float* bk  = (const float*)d_in[5];
    const float* cls = (const float*)d_in[6];

    float* out = (float*)d_out;
    unsigned long long* mem = (unsigned long long*)d_ws;   // B*S masks (16 KB)

    k1_gemm_fill<<<NG_GEMM + NG_FILL, 256, 0, stream>>>(nve, Wq, bq, Wk, bk, out);
    k2_attn<<<N2_ATTN + N2_FILL, 256, 0, stream>>>(out, mem, out);
    k3_finish<<<N3_ROWS + N3_TAIL, 256, 0, stream>>>(nve, cls, mem, out);
}

// Round 6
// 110.807 us; speedup vs baseline: 1.3703x; 1.2094x over previous
//
#include <hip/hip_runtime.h>
#include <math.h>

// Problem constants (fixed by setup_inputs)
constexpr int B = 32;
constexpr int N = 65;    // seq_len + 1
constexpr int D = 512;
constexpr int S = 64;    // N - 1
constexpr int M = B * N; // 2080 rows for the QK projection GEMM

// out0 layout: [B, S, S+1, D] = 68,157,440 floats. The b=31 block
// (last 2,129,920 floats) is EXACTLY q (M*D) + kT (B*D*N) — we stage q/kT
// there, zero-fill b<31 concurrently, and densely rewrite b=31 at the end.
constexpr size_t OUT0_ELEMS = (size_t)B * S * (S + 1) * D;       // 68,157,440
constexpr size_t Q_ELEMS    = (size_t)M * D;                      // 1,064,960
constexpr size_t KT_ELEMS   = (size_t)B * D * N;                  // 1,064,960
constexpr size_t STAGE_BASE = OUT0_ELEMS - Q_ELEMS - KT_ELEMS;    // == b31 start
constexpr int ZF4 = (int)(STAGE_BASE / 4);                        // 16,506,880 float4 zeros

// K1 grid split
constexpr int NG_GEMM = 1040;  // 65 m-tiles x 8 n-tiles x 2 matrices
constexpr int NG_FILL = 1536;
// K4 grid split
constexpr int NC = (B - 1) * S;            // 1984 scatter blocks (b<31)
constexpr int NA = 1040;                   // b31 dense fill: 1040*512 f4 = 532,480
constexpr int NB = 130;                    // leader+member: 130*256 f4 = 33,280

// ---------------------------------------------------------------------------
// K1: fused projection GEMM (q = nve@Wq^T+bq row-major; kT[b][d][n]) plus
// zero-fill of out0[b<31]. GEMM: 1040 blocks (high occupancy), 32x64 tile,
// BK=64, 2x4 microtile, 256 threads, ~25 KB LDS.
// ---------------------------------------------------------------------------
__global__ __launch_bounds__(256) void k1_gemm_fill(
    const float* __restrict__ nve, const float* __restrict__ Wq,
    const float* __restrict__ bq, const float* __restrict__ Wk,
    const float* __restrict__ bk, float* __restrict__ out)
{
    __shared__ float As[64][33];   // [k][m-row]; scalar broadcast reads
    __shared__ float Ws[64][68];   // [k][n-col]; b128 reads (2-way = free)

    const int gid = blockIdx.x;
    const int tid = threadIdx.x;

    if (gid < NG_GEMM) {
        const int mat = gid >= (NG_GEMM / 2);
        const int t   = mat ? gid - NG_GEMM / 2 : gid;
        const int bm  = (t % 65) * 32;     // 65*32 = 2080 = M exactly: no bounds
        const int bn  = (t / 65) * 64;
        const float* W    = mat ? Wk : Wq;
        const float* bias = mat ? bk : bq;

        float* q  = out + STAGE_BASE;      // [M][D]
        float* kT = q + Q_ELEMS;           // [B][D][N]

        const int tn4 = (tid & 15) * 4;    // 4 output cols
        const int tm2 = (tid >> 4) * 2;    // 2 output rows

        float4 acc0 = make_float4(0.f, 0.f, 0.f, 0.f);
        float4 acc1 = make_float4(0.f, 0.f, 0.f, 0.f);

        for (int k0 = 0; k0 < D; k0 += 64) {
            #pragma unroll
            for (int p = 0; p < 2; ++p) {      // A tile: 32 rows x 16 f4
                const int idx = p * 256 + tid;
                const int row = idx >> 4;
                const int c4  = (idx & 15) * 4;
                const float4 v = *(const float4*)&nve[(size_t)(bm + row) * D + k0 + c4];
                As[c4 + 0][row] = v.x; As[c4 + 1][row] = v.y;
                As[c4 + 2][row] = v.z; As[c4 + 3][row] = v.w;
            }
            #pragma unroll
            for (int p = 0; p < 4; ++p) {      // W tile: 64 n-rows x 16 f4
                const int idx = p * 256 + tid;
                const int row = idx >> 4;
                const int c4  = (idx & 15) * 4;
                const float4 v = *(const float4*)&W[(size_t)(bn + row) * D + k0 + c4];
                Ws[c4 + 0][row] = v.x; Ws[c4 + 1][row] = v.y;
                Ws[c4 + 2][row] = v.z; Ws[c4 + 3][row] = v.w;
            }
            __syncthreads();

            #pragma unroll
            for (int kk = 0; kk < 64; ++kk) {
                const float a0 = As[kk][tm2];
                const float a1 = As[kk][tm2 + 1];
                const float4 w = *(const float4*)&Ws[kk][tn4];
                acc0.x += a0 * w.x; acc0.y += a0 * w.y;
                acc0.z += a0 * w.z; acc0.w += a0 * w.w;
                acc1.x += a1 * w.x; acc1.y += a1 * w.y;
                acc1.z += a1 * w.z; acc1.w += a1 * w.w;
            }
            __syncthreads();
        }

        const int gm0 = bm + tm2;
        const float4 b4 = *(const float4*)&bias[bn + tn4];
        if (mat == 0) {
            float4 r;
            r.x = acc0.x + b4.x; r.y = acc0.y + b4.y;
            r.z = acc0.z + b4.z; r.w = acc0.w + b4.w;
            *(float4*)&q[(size_t)gm0 * D + bn + tn4] = r;
            r.x = acc1.x + b4.x; r.y = acc1.y + b4.y;
            r.z = acc1.z + b4.z; r.w = acc1.w + b4.w;
            *(float4*)&q[(size_t)(gm0 + 1) * D + bn + tn4] = r;
        } else {
            #pragma unroll
            for (int rr = 0; rr < 2; ++rr) {
                const int gm = gm0 + rr;
                const int b = gm / N;
                const int n = gm % N;
                const float* ac = rr ? (const float*)&acc1 : (const float*)&acc0;
                const float* bi = (const float*)&b4;
                #pragma unroll
                for (int j = 0; j < 4; ++j) {
                    const int gd = bn + tn4 + j;
                    kT[(size_t)b * D * N + (size_t)gd * N + n] = ac[j] + bi[j];
                }
            }
        }
    } else {
        // zero-fill out0[b < 31] (float4 grid-stride)
        const float4 z = make_float4(0.f, 0.f, 0.f, 0.f);
        float4* o4 = (float4*)out;
        const int nthr = NG_FILL * 256;
        for (int f = (gid - NG_GEMM) * 256 + tid; f < ZF4; f += nthr)
            o4[f] = z;
    }
}

// ---------------------------------------------------------------------------
// K2: per (b,i), i in 1..64: scores over 65 cols (diag of [1:,1:] zeroed
// pre-softmax), softmax, member bits = (prob > 0.05) | eye -> 64-bit mask.
// ---------------------------------------------------------------------------
__global__ __launch_bounds__(128) void k2_attn(
    const float* __restrict__ out, unsigned long long* __restrict__ mem)
{
    const float* q  = out + STAGE_BASE;
    const float* kT = q + Q_ELEMS;

    const int bi = blockIdx.x;     // 0..B*S-1
    const int b = bi / S;
    const int r = bi % S;
    const int i = r + 1;
    const int t = threadIdx.x;

    __shared__ float qrow[D];
    __shared__ float sc[N];

    *(float4*)&qrow[t * 4] = *(const float4*)&q[((size_t)b * N + i) * D + t * 4];
    __syncthreads();

    if (t < N) {
        const float* kp = &kT[(size_t)b * D * N];
        float acc = 0.f;
        for (int e = 0; e < D; ++e) acc += qrow[e] * kp[(size_t)e * N + t];
        float s = acc * 0.044194173824159216f;  // 1/sqrt(512)
        if (t == i) s = 0.f;
        sc[t] = s;
    }
    __syncthreads();

    if (t < 64) {
        float mx = -INFINITY;
        for (int j = 0; j < N; ++j) mx = fmaxf(mx, sc[j]);
        float sum = 0.f;
        for (int j = 0; j < N; ++j) sum += expf(sc[j] - mx);
        const float p = expf(sc[t + 1] - mx) / sum;
        const bool bit = (p > 0.05f) || (t + 1 == i);
        unsigned long long mask = __ballot(bit);
        if (t == 0) mem[bi] = mask;
    }
}

// ---------------------------------------------------------------------------
// K3: greedy sequential clustering — one thread per batch.
// ---------------------------------------------------------------------------
__global__ void k3_cluster(const unsigned long long* __restrict__ mem,
                           unsigned long long* __restrict__ sel,
                           unsigned long long* __restrict__ lead)
{
    const int b = threadIdx.x;
    if (b >= B) return;
    unsigned long long used = 0ull, lb = 0ull;
    for (int i = 0; i < S; ++i) {
        const unsigned long long row = mem[b * S + i];
        const bool active = !((used >> i) & 1ull);
        const unsigned long long sl = active ? row : 0ull;
        used |= sl;
        lb |= (unsigned long long)active << i;
        sel[b * S + i] = sl;
    }
    lead[b] = lb;
}

// ---------------------------------------------------------------------------
// K4: (C) scatter nonzero rows for b<31; (A) dense bit-gated fill of the
// b=31 block (overwrites the q/kT staging); (B) leader/member outputs.
// ---------------------------------------------------------------------------
__global__ __launch_bounds__(256) void k4_finish(
    const float* __restrict__ nve, const float* __restrict__ cls,
    const unsigned long long* __restrict__ sel,
    const unsigned long long* __restrict__ lead,
    float* __restrict__ out)
{
    const int gid = blockIdx.x;
    const int t = threadIdx.x;

    if (gid < NC) {
        // scatter for b in [0,31): one block per (b,i) row
        const int b = gid / S;
        const int i = gid % S;
        const unsigned long long lb = lead[b];
        const unsigned long long sb = sel[b * S + i];
        const int h = t >> 7;          // 0/1: two columns in parallel
        const int tt = t & 127;        // f4 index within a 512-float slot
        float4* slot0 = (float4*)(out + (((size_t)b * S + i) * (S + 1)) * D);
        for (int s = h; s <= S; s += 2) {
            bool on = (s == 0) ? ((lb >> i) & 1ull) : ((sb >> (s - 1)) & 1ull);
            if (!on) continue;
            const float* src = (s == 0) ? cls : &nve[((size_t)b * N + s) * D];
            slot0[(size_t)s * 128 + tt] = ((const float4*)src)[tt];
        }
    } else if (gid < NC + NA) {
        // dense fill of b=31 region: 532,480 f4, 512 per block
        const int ablk = gid - NC;
        const unsigned long long lb = lead[B - 1];
        float4* base4 = (float4*)out + STAGE_BASE / 4;
        #pragma unroll
        for (int u = 0; u < 2; ++u) {
            const int f = ablk * 512 + u * 256 + t;
            const int d4 = f & 127;
            const int slot = f >> 7;         // 0..4159
            const int s = slot % (S + 1);
            const int i = slot / (S + 1);
            bool on;
            const float* src;
            if (s == 0) {
                on = (lb >> i) & 1ull;
                src = &cls[d4 * 4];
            } else {
                on = (sel[(B - 1) * S + i] >> (s - 1)) & 1ull;
                src = &nve[((size_t)(B - 1) * N + s) * D + d4 * 4];
            }
            float4 v = make_float4(0.f, 0.f, 0.f, 0.f);
            if (on) v = *(const float4*)src;
            base4[f] = v;
        }
    } else {
        // leader [B,S] then member [B,S,S] floats, f4-stored
        const int f = (gid - NC - NA) * 256 + t;   // f4 index
        float* tail = out + OUT0_ELEMS;
        float4 v;
        #pragma unroll
        for (int c = 0; c < 4; ++c) {
            const int idx = f * 4 + c;
            float x;
            if (idx < B * S) {
                x = (float)((lead[idx / S] >> (idx % S)) & 1ull);
            } else {
                const int m = idx - B * S;   // < B*S*S
                const int b = m / (S * S);
                const int rem = m % (S * S);
                x = (float)((sel[b * S + rem / S] >> (rem % S)) & 1ull);
            }
            ((float*)&v)[c] = x;
        }
        *(float4*)&tail[(size_t)f * 4] = v;
    }
}

extern "C" void kernel_launch(void* const* d_in, const int* in_sizes, int n_in,
                              void* d_out, int out_size, void* d_ws, size_t ws_size,
                              hipStream_t stream) {
    // inputs: 0=desc(unused) 1=nve 2=Wq 3=bq 4=Wk 5=bk 6=cls
    const float* nve = (const float*)d_in[1];
    const float* Wq  = (const float*)d_in[2];
    const float* bq  = (const float*)d_in[3];
    const float* Wk  = (const float*)d_in[4];
    const float* bk  = (const float*)d_in[5];
    const float* cls = (const float*)d_in[6];

    float* out = (float*)d_out;

    unsigned long long* mem  = (unsigned long long*)d_ws;       // B*S
    unsigned long long* sel  = mem + B * S;                     // B*S
    unsigned long long* lead = sel + B * S;                     // B

    k1_gemm_fill<<<NG_GEMM + NG_FILL, 256, 0, stream>>>(nve, Wq, bq, Wk, bk, out);
    k2_attn<<<B * S, 128, 0, stream>>>(out, mem);
    k3_cluster<<<1, 64, 0, stream>>>(mem, sel, lead);
    k4_finish<<<NC + NA + NB, 256, 0, stream>>>(nve, cls, sel, lead, out);
}